// Round 4
// baseline (1508.219 us; speedup 1.0000x reference)
//
#include <hip/hip_runtime.h>

// EM recurrent cross-attention, MI355X (gfx950). Round 3 (resubmit after
// GPU-acquisition timeout; never benched).
// C=32, H=4, F=64, N=200000, 2 EM steps (one kernel launch each).
// R2 post-mortem: compiler allocated 64 VGPR for ~96 live values -> spills
// (WRITE_SIZE 36MB) -> latency-bound at 24% VALU / 35% occ. R3:
//  - quarter-granularity K-row prefetch (<=3 quarters in flight, 48 regs)
//  - peak live set ~112 regs, __launch_bounds__(512,4) caps at 128 (no spill)
//  - N%64==0 -> no validity clamps in the hot loop
//  - 8-deep V double buffer, int-offset addressing
// Per wave: 64 n's. Phase1 lane=n (in-lane softmax over 32 clusters),
// LDS transpose of w, phase2 lane=f register acc. Block reduce + atomicAdd.

#define CC 32
#define HH 4
#define FF 64
#define NB 64
#define WAVES 8
#define BLOCK 512
#define GX 128          // 128 x 4 heads = 512 blocks = 2/CU (LDS-limited)
#define HF (HH * FF)    // 256 floats per n-row

typedef float f32x2 __attribute__((ext_vector_type(2)));

__device__ __forceinline__ void pkfma(f32x2& d, f32x2 a, f32x2 b) {
    // D.lo += a.lo*b.lo ; D.hi += a.hi*b.hi  (one VALU issue for 2 fp32 FMAs)
    asm("v_pk_fma_f32 %0, %1, %2, %0" : "+v"(d) : "v"(a), "v"(b));
}

__global__ __launch_bounds__(BLOCK, 4) void em_step_kernel(
    const float* __restrict__ cent_in,   // (C,H,F)
    const float* __restrict__ Kp,        // (N,H,F)
    const float* __restrict__ Vp,        // (N,H,F)
    float* __restrict__ cent_out,        // (C,H,F), pre-zeroed atomicAdd target
    int N)
{
    const int h    = blockIdx.y;
    const int tid  = threadIdx.x;
    const int wid  = tid >> 6;
    const int lane = tid & 63;

    __shared__ float centT[FF][CC];            // 8 KB, transposed [f][c], x0.125
    __shared__ float wlds[WAVES][NB][36];      // 72 KB (144B rows, 16B aligned)

    for (int i = tid; i < CC * FF; i += BLOCK) {
        int c = i & (CC - 1), f = i >> 5;
        centT[f][c] = cent_in[(c * HH + h) * FF + f] * 0.125f;
    }
    __syncthreads();

    f32x2 acc2[16];                            // lane=f accumulator, pairs over c
    #pragma unroll
    for (int p = 0; p < 16; ++p) acc2[p] = f32x2{0.f, 0.f};

    const int ngroups = N / NB;                // 3125 (N % 64 == 0)
    const int gstep   = GX * WAVES;            // 1024
    const int g0      = blockIdx.x * WAVES + wid;

    // ---- K quarter-row prefetch: 4 float4 = 16 f-values per quarter ----
    auto issueKq = [&](float4 (&kb)[4], int g, int quar) {
        int gg = g < ngroups ? g : (ngroups - 1);
        const float4* Kr =
            (const float4*)(Kp + (gg * NB + lane) * HF + h * FF) + quar * 4;
        #pragma unroll
        for (int q = 0; q < 4; ++q) kb[q] = Kr[q];
    };

    auto qkq = [&](const float4 (&kb)[4], int quar, f32x2 (&s2)[16]) {
        #pragma unroll
        for (int q = 0; q < 4; ++q) {
            float kv[4] = {kb[q].x, kb[q].y, kb[q].z, kb[q].w};
            #pragma unroll
            for (int ff = 0; ff < 4; ++ff) {
                f32x2 kk = {kv[ff], kv[ff]};
                const float4* crow = (const float4*)&centT[quar * 16 + q * 4 + ff][0];
                #pragma unroll
                for (int c8 = 0; c8 < 8; ++c8) {
                    float4 ce = crow[c8];      // uniform addr -> LDS broadcast
                    pkfma(s2[c8 * 2 + 0], kk, f32x2{ce.x, ce.y});
                    pkfma(s2[c8 * 2 + 1], kk, f32x2{ce.z, ce.w});
                }
            }
        }
    };

    float4 kp0[4];
    issueKq(kp0, g0, 0);                       // quarter 0 of first group

    for (int g = g0; g < ngroups; g += gstep) {
        // ---------- phase 1: scores for n = g*64 + lane ----------
        float4 kq1[4], kq2[4], kq3[4];
        issueKq(kq1, g, 1);                    // in flight during q0 compute

        f32x2 s2[16];
        #pragma unroll
        for (int p = 0; p < 16; ++p) s2[p] = f32x2{0.f, 0.f};

        qkq(kp0, 0, s2);
        issueKq(kq2, g, 2);
        qkq(kq1, 1, s2);
        issueKq(kq3, g, 3);
        qkq(kq2, 2, s2);
        qkq(kq3, 3, s2);

        // ---------- in-lane softmax over 32 clusters ----------
        float m = -3.0e38f;
        #pragma unroll
        for (int p = 0; p < 16; ++p) m = fmaxf(m, fmaxf(s2[p].x, s2[p].y));
        float sum = 0.f;
        #pragma unroll
        for (int p = 0; p < 16; ++p) {
            s2[p].x = __expf(s2[p].x - m); sum += s2[p].x;
            s2[p].y = __expf(s2[p].y - m); sum += s2[p].y;
        }
        float r = 1.0f / sum;

        float4* wr = (float4*)&wlds[wid][lane][0];
        #pragma unroll
        for (int c4 = 0; c4 < 8; ++c4) {
            float4 w4;
            w4.x = s2[2 * c4].x     * r;
            w4.y = s2[2 * c4].y     * r;
            w4.z = s2[2 * c4 + 1].x * r;
            w4.w = s2[2 * c4 + 1].y * r;
            wr[c4] = w4;                       // same-wave produce/consume
        }

        // prefetch next group's quarter 0 (hides under all of phase 2)
        issueKq(kp0, g + gstep, 0);

        // ---------- phase 2: acc[c][f=lane] += w[j][c] * V[j][f] ----------
        const float* Vb = Vp + g * NB * HF + h * FF + lane;

        float va[8], vb[8];
        auto loadv = [&](float (&buf)[8], int jb) {
            const float* p = Vb + jb * HF;
            #pragma unroll
            for (int jj = 0; jj < 8; ++jj) buf[jj] = p[jj * HF];  // coalesced
        };
        auto pv = [&](const float (&buf)[8], int jb) {
            #pragma unroll
            for (int jj = 0; jj < 8; ++jj) {
                f32x2 vv = {buf[jj], buf[jj]};
                const float4* wrow = (const float4*)&wlds[wid][jb + jj][0];
                #pragma unroll
                for (int c4 = 0; c4 < 8; ++c4) {
                    float4 w4 = wrow[c4];      // uniform addr -> LDS broadcast
                    pkfma(acc2[2 * c4 + 0], vv, f32x2{w4.x, w4.y});
                    pkfma(acc2[2 * c4 + 1], vv, f32x2{w4.z, w4.w});
                }
            }
        };

        loadv(va, 0);
        loadv(vb, 8);  pv(va, 0);
        loadv(va, 16); pv(vb, 8);
        loadv(vb, 24); pv(va, 16);
        loadv(va, 32); pv(vb, 24);
        loadv(vb, 40); pv(va, 32);
        loadv(va, 48); pv(vb, 40);
        loadv(vb, 56); pv(va, 48);
        pv(vb, 56);
    }

    // ---------- block reduce (overlay on wlds) + global atomics ----------
    __syncthreads();
    float* red = &wlds[0][0][0];               // 8*32*64 floats = 64KB <= 72KB
    #pragma unroll
    for (int p = 0; p < 16; ++p) {
        red[(wid * CC + 2 * p + 0) * FF + lane] = acc2[p].x;
        red[(wid * CC + 2 * p + 1) * FF + lane] = acc2[p].y;
    }
    __syncthreads();
    #pragma unroll
    for (int k = 0; k < (CC * FF) / BLOCK; ++k) {   // 4 iters
        int o = k * BLOCK + tid;
        int c = o >> 6, f = o & 63;
        float val = 0.f;
        #pragma unroll
        for (int w = 0; w < WAVES; ++w) val += red[(w * CC + c) * FF + f];
        atomicAdd(&cent_out[(c * HH + h) * FF + f], val);
    }
}

extern "C" void kernel_launch(void* const* d_in, const int* in_sizes, int n_in,
                              void* d_out, int out_size, void* d_ws, size_t ws_size,
                              hipStream_t stream)
{
    const float* Q = (const float*)d_in[0];   // (C,H,F)
    const float* K = (const float*)d_in[1];   // (N,H,F)
    const float* V = (const float*)d_in[2];   // (N,H,F)
    float*       out   = (float*)d_out;       // (C,H,F)
    float*       cent1 = (float*)d_ws;        // step-1 centroid accumulator

    const int N = in_sizes[1] / (HH * FF);

    hipMemsetAsync(cent1, 0, CC * HH * FF * sizeof(float), stream);
    hipMemsetAsync(out,   0, CC * HH * FF * sizeof(float), stream);

    dim3 grid(GX, HH), block(BLOCK);
    em_step_kernel<<<grid, block, 0, stream>>>(Q,     K, V, cent1, N);  // EM step 1
    em_step_kernel<<<grid, block, 0, stream>>>(cent1, K, V, out,   N);  // EM step 2
}